// Round 3
// baseline (281.768 us; speedup 1.0000x reference)
//
#include <hip/hip_runtime.h>
#include <hip/hip_bf16.h>
#include <stdint.h>

#define EPS_BN 1e-5f

constexpr int Fn = 32;    // frames
constexpr int Pn = 64;    // peds per frame
constexpr int Bn = 2048;  // batch
constexpr int Hn = 128;   // h_dim
constexpr int En = 64;    // embed dim
constexpr int Mn = 512;   // GEMM K
constexpr int Dn = 1024;  // GEMM N

using bf16x8 = __attribute__((ext_vector_type(8))) short;
using f32x4  = __attribute__((ext_vector_type(4))) float;

static __device__ __forceinline__ float    bcf(uint32_t u) { return __builtin_bit_cast(float, u); }
static __device__ __forceinline__ uint32_t bcu(float f)    { return __builtin_bit_cast(uint32_t, f); }
static __device__ __forceinline__ unsigned short bfbits(float f) {
  return __builtin_bit_cast(unsigned short, __float2bfloat16(f));
}

// async 16B global -> LDS (wave-uniform LDS base + lane*16)
static __device__ __forceinline__ void dma16(const uint4* g, uint4* l) {
  __builtin_amdgcn_global_load_lds(
      (const __attribute__((address_space(1))) unsigned int*)g,
      (__attribute__((address_space(3))) unsigned int*)l, 16, 0, 0);
}

// ---------------------------------------------------------------------------
// prep_all: one kernel, 384 blocks x 512 threads.
//  blocks [0,256):  prep1-role (prep0 inlined): Agb/Qgb bf16, BN1 folded.
//  blocks [256,384): prep2-role: W2f in MFMA B-fragment granule order (BN2
//                    scale folded, bf16) + c2.
// ---------------------------------------------------------------------------
__global__ void prep_all(const float* __restrict__ hs, const float* __restrict__ pos,
                         const float* __restrict__ We, const float* __restrict__ be,
                         const float* __restrict__ W1, const float* __restrict__ b1,
                         const float* __restrict__ g1, const float* __restrict__ beta1,
                         const float* __restrict__ rm1, const float* __restrict__ rv1,
                         const float* __restrict__ W2, const float* __restrict__ b2,
                         const float* __restrict__ g2, const float* __restrict__ beta2,
                         const float* __restrict__ rm2, const float* __restrict__ rv2,
                         __hip_bfloat16* __restrict__ Agb, __hip_bfloat16* __restrict__ Qgb,
                         uint4* __restrict__ W2f, float* __restrict__ c2) {
  __shared__ float smem[64 * 65];
  int bid = blockIdx.x, t = threadIdx.x;
  if (bid < 256) {
    // ---- Ag/Qg for 8 batch rows ----
    int rb = bid * 8, m = t;  // m in [0,512)
    float* hsh = smem;        // 1024 floats
    float* psh = smem + 1024; // 16 floats
    for (int idx = t; idx < 8 * Hn; idx += 512) hsh[idx] = hs[rb * Hn + idx];
    if (t < 16) psh[t] = pos[rb * 2 + t];
    __syncthreads();
    // inline prep0: Wr0/Wr1/cb for column m
    float w0 = 0.f, w1 = 0.f, c = 0.f;
    for (int e = 0; e < En; ++e) {
      float w = W1[e * Mn + m];
      w0 += We[e] * w; w1 += We[En + e] * w; c += be[e] * w;
    }
    c += b1[m];
    float s  = g1[m] * rsqrtf(rv1[m] + EPS_BN);
    float tt = beta1[m] - rm1[m] * s;
    float acc[8];
#pragma unroll
    for (int ri = 0; ri < 8; ++ri) acc[ri] = c;
    for (int e = 0; e < Hn; ++e) {
      float w = W1[(En + e) * Mn + m];
#pragma unroll
      for (int ri = 0; ri < 8; ++ri) acc[ri] += hsh[ri * Hn + e] * w;
    }
#pragma unroll
    for (int ri = 0; ri < 8; ++ri) {
      float q = psh[ri * 2] * w0 + psh[ri * 2 + 1] * w1;
      Agb[(rb + ri) * Mn + m] = __float2bfloat16((acc[ri] + q) * s + tt);
      Qgb[(rb + ri) * Mn + m] = __float2bfloat16(q * s);
    }
  } else {
    // ---- W2 transpose into B-fragment granules ----
    int b2i = bid - 256;            // 0..127
    int d0 = (b2i & 15) * 64, k0 = (b2i >> 4) * 64;
    int col = t & 63, row8 = t >> 6;  // 512 threads: 8 rows each
#pragma unroll
    for (int rr = 0; rr < 8; ++rr) {
      int row = rr * 8 + row8;
      smem[row * 65 + col] = W2[(k0 + row) * Dn + d0 + col];  // [k_local][d_local]
    }
    __syncthreads();
    int lane = t & 63, q8 = t >> 6;   // q8 0..7
    int sel = q8 & 3, kcl = q8 >> 2;
    int dl = sel * 16 + (lane & 15), d = d0 + dl;
    float sf = g2[d] * rsqrtf(rv2[d] + EPS_BN);
    int kb = kcl * 32 + (lane >> 4) * 8;
    uint32_t wd[4];
#pragma unroll
    for (int h = 0; h < 4; ++h) {
      uint32_t u0 = bfbits(smem[(kb + 2 * h) * 65 + dl] * sf);
      uint32_t u1 = bfbits(smem[(kb + 2 * h + 1) * 65 + dl] * sf);
      wd[h] = u0 | (u1 << 16);
    }
    int ntile = (d0 >> 4) + sel;
    int kc    = (k0 >> 5) + kcl;
    W2f[(ntile * 16 + kc) * 64 + lane] = (uint4){wd[0], wd[1], wd[2], wd[3]};
    if (k0 == 0 && t < 64) {
      int dd = d0 + t;
      float ss = g2[dd] * rsqrtf(rv2[dd] + EPS_BN);
      c2[dd] = b2[dd] * ss + beta2[dd] - rm2[dd] * ss;
    }
  }
}

// ---------------------------------------------------------------------------
// gemm_pool: BM=128 (2 i x 64 j) x BN=128, BK=32, 16 kc.
//  - Waves split M: wave w owns j-rows [16w,16w+16) for BOTH i's; its MFMA
//    A-fragments are constructed entirely in registers from global bf16
//    Agb (per-lane) and Qgb (broadcast) loads: NO LDS for A.
//  - B (already in fragment granule order) staged via global_load_lds
//    dwordx4, double-buffered; all kc+1 loads issued right after the kc
//    barrier -> a full iteration of slack before the barrier's vmcnt drain.
//  - Epilogue: in-wave max over 16 j (regs + shfl), cross-wave max via 4KB
//    LDS, then +c2 / relu (monotone, deferred past the max), exclusive write.
// ---------------------------------------------------------------------------
__launch_bounds__(256, 3)
__global__ void gemm_pool(const __hip_bfloat16* __restrict__ Agb,
                          const __hip_bfloat16* __restrict__ Qgb,
                          const uint4* __restrict__ W2f,
                          const float* __restrict__ c2, float* __restrict__ out) {
  __shared__ uint4 Bs[2][512];          // 8KB per buffer: 8 granules x 64 uint4
  __shared__ float red_s[4][2][128];    // cross-wave max scratch

  int ct = blockIdx.x;   // 0..7   d-tile
  int rt = blockIdx.y;   // 0..1023 (frame, i-pair)
  int f = rt >> 5, i0 = (rt & 31) * 2;
  int t = threadIdx.x, lane = t & 63, w = t >> 6;

  int jr = w * 16 + (lane & 15);     // this lane's j row
  int ko = (lane >> 4) * 8;          // k-octet within 32-k chunk

  const uint4* aP  = (const uint4*)(Agb + (f * Pn + jr) * Mn + ko);      // +4/kc
  const uint4* q0P = (const uint4*)(Qgb + (f * Pn + i0) * Mn + ko);
  const uint4* q1P = (const uint4*)(Qgb + (f * Pn + i0 + 1) * Mn + ko);
  const uint4* bS0 = W2f + ((ct * 8 + 2 * w) * 16) * 64 + lane;          // +64/kc
  const uint4* bS1 = W2f + ((ct * 8 + 2 * w + 1) * 16) * 64 + lane;

  // prologue: stage B(0), load a/q(0)
  dma16(bS0, &Bs[0][(2 * w) * 64]);
  dma16(bS1, &Bs[0][(2 * w + 1) * 64]);
  uint4 rA = aP[0], rQ0 = q0P[0], rQ1 = q1P[0];

  f32x4 acc0[8], acc1[8];
#pragma unroll
  for (int nt = 0; nt < 8; ++nt) {
    acc0[nt] = (f32x4){0.f, 0.f, 0.f, 0.f};
    acc1[nt] = (f32x4){0.f, 0.f, 0.f, 0.f};
  }

#pragma unroll
  for (int kc = 0; kc < 16; ++kc) {
    int p = kc & 1;
    __syncthreads();  // vmcnt(0): B(kc) + a/q(kc) arrived (issued a full iter ago)

    // issue bg reads early
    bf16x8 bg[8];
#pragma unroll
    for (int nt = 0; nt < 8; ++nt)
      bg[nt] = *(const bf16x8*)&Bs[p][nt * 64 + lane];

    // prefetch kc+1 (B via DMA into other buffer, a/q into regs)
    uint4 nA = rA, nQ0 = rQ0, nQ1 = rQ1;
    if (kc < 15) {
      dma16(bS0 + (kc + 1) * 64, &Bs[p ^ 1][(2 * w) * 64]);
      dma16(bS1 + (kc + 1) * 64, &Bs[p ^ 1][(2 * w + 1) * 64]);
      nA  = aP[(kc + 1) * 4];
      nQ0 = q0P[(kc + 1) * 4];
      nQ1 = q1P[(kc + 1) * 4];
    }

    // construct af = relu(Ag - Qg) in registers (bf16 truncation via v_perm)
    uint4 x0, x1;
#pragma unroll
    for (int v = 0; v < 4; ++v) {
      uint32_t aw  = ((const uint32_t*)&rA)[v];
      uint32_t q0w = ((const uint32_t*)&rQ0)[v];
      uint32_t q1w = ((const uint32_t*)&rQ1)[v];
      float alo = bcf(aw << 16), ahi = bcf(aw);   // hi: low-16 garbage mantissa, < 2^-16 rel
      float x0lo = fmaxf(alo - bcf(q0w << 16), 0.f);
      float x0hi = fmaxf(ahi - bcf(q0w), 0.f);
      float x1lo = fmaxf(alo - bcf(q1w << 16), 0.f);
      float x1hi = fmaxf(ahi - bcf(q1w), 0.f);
      ((uint32_t*)&x0)[v] = __builtin_amdgcn_perm(bcu(x0hi), bcu(x0lo), 0x07060302u);
      ((uint32_t*)&x1)[v] = __builtin_amdgcn_perm(bcu(x1hi), bcu(x1lo), 0x07060302u);
    }
    bf16x8 af0 = __builtin_bit_cast(bf16x8, x0);
    bf16x8 af1 = __builtin_bit_cast(bf16x8, x1);

#pragma unroll
    for (int nt = 0; nt < 8; ++nt) {
      acc0[nt] = __builtin_amdgcn_mfma_f32_16x16x32_bf16(af0, bg[nt], acc0[nt], 0, 0, 0);
      acc1[nt] = __builtin_amdgcn_mfma_f32_16x16x32_bf16(af1, bg[nt], acc1[nt], 0, 0, 0);
    }
    rA = nA; rQ0 = nQ0; rQ1 = nQ1;
  }

  // ---- epilogue: max over j, then +c2 / relu, exclusive write ----
#pragma unroll
  for (int nt = 0; nt < 8; ++nt) {
    float m0 = fmaxf(fmaxf(acc0[nt][0], acc0[nt][1]), fmaxf(acc0[nt][2], acc0[nt][3]));
    float m1 = fmaxf(fmaxf(acc1[nt][0], acc1[nt][1]), fmaxf(acc1[nt][2], acc1[nt][3]));
    m0 = fmaxf(m0, __shfl_xor(m0, 16));
    m0 = fmaxf(m0, __shfl_xor(m0, 32));
    m1 = fmaxf(m1, __shfl_xor(m1, 16));
    m1 = fmaxf(m1, __shfl_xor(m1, 32));
    if (lane < 16) {
      red_s[w][0][nt * 16 + lane] = m0;
      red_s[w][1][nt * 16 + lane] = m1;
    }
  }
  __syncthreads();
  int is = t >> 7, dl = t & 127;
  float v = fmaxf(fmaxf(red_s[0][is][dl], red_s[1][is][dl]),
                  fmaxf(red_s[2][is][dl], red_s[3][is][dl]));
  out[(f * Pn + i0 + is) * Dn + ct * 128 + dl] = fmaxf(v + c2[ct * 128 + dl], 0.f);
}

// ---------------------------------------------------------------------------
extern "C" void kernel_launch(void* const* d_in, const int* in_sizes, int n_in,
                              void* d_out, int out_size, void* d_ws, size_t ws_size,
                              hipStream_t stream) {
  const float* hs    = (const float*)d_in[0];
  const float* pos   = (const float*)d_in[1];
  // d_in[2] seq_start_end: unused (equal-size frames, P=64)
  const float* We    = (const float*)d_in[3];
  const float* be    = (const float*)d_in[4];
  const float* W1    = (const float*)d_in[5];
  const float* b1    = (const float*)d_in[6];
  const float* g1    = (const float*)d_in[7];
  const float* beta1 = (const float*)d_in[8];
  const float* W2    = (const float*)d_in[9];
  const float* b2    = (const float*)d_in[10];
  const float* g2    = (const float*)d_in[11];
  const float* beta2 = (const float*)d_in[12];
  const float* rm1   = (const float*)d_in[13];
  const float* rv1   = (const float*)d_in[14];
  const float* rm2   = (const float*)d_in[15];
  const float* rv2   = (const float*)d_in[16];

  char* ws = (char*)d_ws;
  // layout: c2 4KB | Agb 2MB | Qgb 2MB | W2f 1MB
  float* c2 = (float*)(ws + 0);
  __hip_bfloat16* Agb = (__hip_bfloat16*)(ws + 4096);
  __hip_bfloat16* Qgb = (__hip_bfloat16*)(ws + 4096 + 2097152);
  uint4* W2f = (uint4*)(ws + 4096 + 2 * 2097152);
  float* out = (float*)d_out;

  prep_all<<<384, 512, 0, stream>>>(hs, pos, We, be, W1, b1, g1, beta1, rm1, rv1,
                                    W2, b2, g2, beta2, rm2, rv2, Agb, Qgb, W2f, c2);
  gemm_pool<<<dim3(Dn / 128, (Bn * Pn) / 128), 256, 0, stream>>>(Agb, Qgb, W2f, c2, out);
}

// Round 4
// 268.503 us; speedup vs baseline: 1.0494x; 1.0494x over previous
//
#include <hip/hip_runtime.h>
#include <hip/hip_bf16.h>
#include <stdint.h>

#define EPS_BN 1e-5f

constexpr int Fn = 32;    // frames
constexpr int Pn = 64;    // peds per frame
constexpr int Bn = 2048;  // batch
constexpr int Hn = 128;   // h_dim
constexpr int En = 64;    // embed dim
constexpr int Mn = 512;   // GEMM K
constexpr int Dn = 1024;  // GEMM N

using bf16x8 = __attribute__((ext_vector_type(8))) short;
using f32x4  = __attribute__((ext_vector_type(4))) float;

static __device__ __forceinline__ float    bcf(uint32_t u) { return __builtin_bit_cast(float, u); }
static __device__ __forceinline__ uint32_t bcu(float f)    { return __builtin_bit_cast(uint32_t, f); }
static __device__ __forceinline__ unsigned short bfbits(float f) {
  return __builtin_bit_cast(unsigned short, __float2bfloat16(f));
}

// async 16B/lane global -> LDS (wave-uniform LDS base + lane*16)
static __device__ __forceinline__ void dma16(const uint4* g, uint4* l) {
  __builtin_amdgcn_global_load_lds(
      (const __attribute__((address_space(1))) unsigned int*)g,
      (__attribute__((address_space(3))) unsigned int*)l, 16, 0, 0);
}

// af = bf16(relu(Ag - Qg)) from packed bf16 pairs (hi path keeps garbage low
// mantissa bits: < 2^-9 rel err, then truncated to bf16 anyway; validated R2/R3)
static __device__ __forceinline__ bf16x8 mk_af(uint4 a, uint4 q) {
  uint4 x;
#pragma unroll
  for (int v = 0; v < 4; ++v) {
    uint32_t aw = ((const uint32_t*)&a)[v], qw = ((const uint32_t*)&q)[v];
    float lo = fmaxf(bcf(aw << 16) - bcf(qw << 16), 0.f);
    float hi = fmaxf(bcf(aw) - bcf(qw), 0.f);
    ((uint32_t*)&x)[v] = __builtin_amdgcn_perm(bcu(hi), bcu(lo), 0x07060302u);
  }
  return __builtin_bit_cast(bf16x8, x);
}

// ---------------------------------------------------------------------------
// prep_all (unchanged from R3): 384 blocks x 512 threads.
//  [0,256):  Agb/Qgb bf16, BN1+embedding folded.
//  [256,384): W2f in MFMA B-fragment granule order (BN2 scale folded) + c2.
// ---------------------------------------------------------------------------
__global__ void prep_all(const float* __restrict__ hs, const float* __restrict__ pos,
                         const float* __restrict__ We, const float* __restrict__ be,
                         const float* __restrict__ W1, const float* __restrict__ b1,
                         const float* __restrict__ g1, const float* __restrict__ beta1,
                         const float* __restrict__ rm1, const float* __restrict__ rv1,
                         const float* __restrict__ W2, const float* __restrict__ b2,
                         const float* __restrict__ g2, const float* __restrict__ beta2,
                         const float* __restrict__ rm2, const float* __restrict__ rv2,
                         __hip_bfloat16* __restrict__ Agb, __hip_bfloat16* __restrict__ Qgb,
                         uint4* __restrict__ W2f, float* __restrict__ c2) {
  __shared__ float smem[64 * 65];
  int bid = blockIdx.x, t = threadIdx.x;
  if (bid < 256) {
    int rb = bid * 8, m = t;
    float* hsh = smem;
    float* psh = smem + 1024;
    for (int idx = t; idx < 8 * Hn; idx += 512) hsh[idx] = hs[rb * Hn + idx];
    if (t < 16) psh[t] = pos[rb * 2 + t];
    __syncthreads();
    float w0 = 0.f, w1 = 0.f, c = 0.f;
    for (int e = 0; e < En; ++e) {
      float w = W1[e * Mn + m];
      w0 += We[e] * w; w1 += We[En + e] * w; c += be[e] * w;
    }
    c += b1[m];
    float s  = g1[m] * rsqrtf(rv1[m] + EPS_BN);
    float tt = beta1[m] - rm1[m] * s;
    float acc[8];
#pragma unroll
    for (int ri = 0; ri < 8; ++ri) acc[ri] = c;
    for (int e = 0; e < Hn; ++e) {
      float w = W1[(En + e) * Mn + m];
#pragma unroll
      for (int ri = 0; ri < 8; ++ri) acc[ri] += hsh[ri * Hn + e] * w;
    }
#pragma unroll
    for (int ri = 0; ri < 8; ++ri) {
      float q = psh[ri * 2] * w0 + psh[ri * 2 + 1] * w1;
      Agb[(rb + ri) * Mn + m] = __float2bfloat16((acc[ri] + q) * s + tt);
      Qgb[(rb + ri) * Mn + m] = __float2bfloat16(q * s);
    }
  } else {
    int b2i = bid - 256;
    int d0 = (b2i & 15) * 64, k0 = (b2i >> 4) * 64;
    int col = t & 63, row8 = t >> 6;
#pragma unroll
    for (int rr = 0; rr < 8; ++rr) {
      int row = rr * 8 + row8;
      smem[row * 65 + col] = W2[(k0 + row) * Dn + d0 + col];
    }
    __syncthreads();
    int lane = t & 63, q8 = t >> 6;
    int sel = q8 & 3, kcl = q8 >> 2;
    int dl = sel * 16 + (lane & 15), d = d0 + dl;
    float sf = g2[d] * rsqrtf(rv2[d] + EPS_BN);
    int kb = kcl * 32 + (lane >> 4) * 8;
    uint32_t wd[4];
#pragma unroll
    for (int h = 0; h < 4; ++h) {
      uint32_t u0 = bfbits(smem[(kb + 2 * h) * 65 + dl] * sf);
      uint32_t u1 = bfbits(smem[(kb + 2 * h + 1) * 65 + dl] * sf);
      wd[h] = u0 | (u1 << 16);
    }
    int ntile = (d0 >> 4) + sel;
    int kc    = (k0 >> 5) + kcl;
    W2f[(ntile * 16 + kc) * 64 + lane] = (uint4){wd[0], wd[1], wd[2], wd[3]};
    if (k0 == 0 && t < 64) {
      int dd = d0 + t;
      float ss = g2[dd] * rsqrtf(rv2[dd] + EPS_BN);
      c2[dd] = b2[dd] * ss + beta2[dd] - rm2[dd] * ss;
    }
  }
}

// ---------------------------------------------------------------------------
// gemm_pool: BM = 4 i's x 64 j = 256 rows, BN = 128, K = 512.
//  - Wave (jw,dw): j in [32*jw, +32) (2 m-tiles), d in [64*dw, +64) (4 granules),
//    all 4 i's. 32 MFMAs per kc, acc = 128 VGPR -> 4x B-fragment reuse:
//    only 4 ds_read_b128 per thread per kc (LDS no longer the bottleneck).
//  - B staged once per 256-k phase into 64KB LDS via global_load_lds; only 2
//    vmcnt-draining barriers per block. Inner 8-kc loop is BARRIER-FREE; A/Q
//    global->reg prefetch (one kc ahead) pipelines across iterations.
//  - A constructed in registers: af = bf16(relu(Ag - Qg_i)).
//  - Epilogue: in-lane/在shfl max over 32 j, cross-jw max via LDS overlay on Bs.
// ---------------------------------------------------------------------------
__launch_bounds__(256, 2)
__global__ void gemm_pool(const __hip_bfloat16* __restrict__ Agb,
                          const __hip_bfloat16* __restrict__ Qgb,
                          const uint4* __restrict__ W2f,
                          const float* __restrict__ c2, float* __restrict__ out) {
  __shared__ uint4 Bs[4096];  // 64KB: [kc8][gnt][lane] = (kc8*8+gnt)*64+lane

  int ct = blockIdx.x;   // 0..7   d-tile of 128
  int rt = blockIdx.y;   // 0..511 (frame, i-quad)
  int f = rt >> 4, i0 = (rt & 15) * 4;

  int t = threadIdx.x, lane = t & 63, w = t >> 6;
  int jw = w & 1, dw = w >> 1;
  int dw4 = dw * 4;

  int jr0 = 32 * jw + (lane & 15);   // m-tile 0 row
  int ko  = (lane >> 4) * 8;         // k-octet within 32-k chunk

  const uint4* aP0 = (const uint4*)(Agb + (f * Pn + jr0) * Mn + ko);        // +4/kc
  const uint4* aP1 = (const uint4*)(Agb + (f * Pn + jr0 + 16) * Mn + ko);
  const uint4* qP0 = (const uint4*)(Qgb + (f * Pn + i0 + 0) * Mn + ko);
  const uint4* qP1 = (const uint4*)(Qgb + (f * Pn + i0 + 1) * Mn + ko);
  const uint4* qP2 = (const uint4*)(Qgb + (f * Pn + i0 + 2) * Mn + ko);
  const uint4* qP3 = (const uint4*)(Qgb + (f * Pn + i0 + 3) * Mn + ko);
  const uint4* W2base = W2f + (size_t)(ct * 8) * 16 * 64 + lane;  // +(gnt*16+kc)*64

  f32x4 acc[4][2][4];  // [i][mt][nt]
#pragma unroll
  for (int i = 0; i < 4; ++i)
#pragma unroll
    for (int mt = 0; mt < 2; ++mt)
#pragma unroll
      for (int nt = 0; nt < 4; ++nt) acc[i][mt][nt] = (f32x4){0.f, 0.f, 0.f, 0.f};

  // prologue A/Q for kc=0
  uint4 rA0 = aP0[0], rA1 = aP1[0];
  uint4 rQ0 = qP0[0], rQ1 = qP1[0], rQ2 = qP2[0], rQ3 = qP3[0];

  for (int ph = 0; ph < 2; ++ph) {
    if (ph) __syncthreads();  // all waves done reading Bs (phase 0)
    // ---- stage this phase's 64KB of B: wave w stages granule-slots [16w,16w+16) ----
#pragma unroll
    for (int s = 0; s < 16; ++s) {
      int idx = w * 16 + s;
      int kc8 = idx >> 3, gnt = idx & 7;
      dma16(W2base + (gnt * 16 + ph * 8 + kc8) * 64, Bs + idx * 64);
    }
    __syncthreads();  // vmcnt(0) drain: Bs ready (only drain point per phase)

    for (int kc8 = 0; kc8 < 8; ++kc8) {
      int kc = ph * 8 + kc8;
      // B fragments for this kc (lane-contiguous b128, conflict-free)
      bf16x8 bg[4];
#pragma unroll
      for (int nt = 0; nt < 4; ++nt)
        bg[nt] = *(const bf16x8*)(Bs + (kc8 * 8 + dw4 + nt) * 64 + lane);

      // prefetch next kc's A/Q (consumed next iteration; 32 MFMAs of slack)
      int kn = (kc < 15) ? kc + 1 : 15;
      uint4 nA0 = aP0[kn * 4], nA1 = aP1[kn * 4];
      uint4 nQ0 = qP0[kn * 4], nQ1 = qP1[kn * 4];
      uint4 nQ2 = qP2[kn * 4], nQ3 = qP3[kn * 4];

      // ---- 4 i's x 2 m-tiles x 4 granules ----
#pragma unroll
      for (int i = 0; i < 4; ++i) {
        uint4 q = (i == 0) ? rQ0 : (i == 1) ? rQ1 : (i == 2) ? rQ2 : rQ3;
        bf16x8 af0 = mk_af(rA0, q);
        bf16x8 af1 = mk_af(rA1, q);
#pragma unroll
        for (int nt = 0; nt < 4; ++nt) {
          acc[i][0][nt] = __builtin_amdgcn_mfma_f32_16x16x32_bf16(af0, bg[nt], acc[i][0][nt], 0, 0, 0);
          acc[i][1][nt] = __builtin_amdgcn_mfma_f32_16x16x32_bf16(af1, bg[nt], acc[i][1][nt], 0, 0, 0);
        }
      }
      rA0 = nA0; rA1 = nA1;
      rQ0 = nQ0; rQ1 = nQ1; rQ2 = nQ2; rQ3 = nQ3;
    }
  }

  // ---- epilogue: max over j (32 in-wave, cross-jw via LDS), +c2, relu ----
  __syncthreads();  // everyone done with Bs; reuse as reduction scratch
  float* redf = (float*)Bs;  // [jw(2)][i(4)][d(128)]
#pragma unroll
  for (int i = 0; i < 4; ++i) {
#pragma unroll
    for (int nt = 0; nt < 4; ++nt) {
      f32x4 a0 = acc[i][0][nt], a1 = acc[i][1][nt];
      float mx = fmaxf(fmaxf(fmaxf(a0[0], a0[1]), fmaxf(a0[2], a0[3])),
                       fmaxf(fmaxf(a1[0], a1[1]), fmaxf(a1[2], a1[3])));
      mx = fmaxf(mx, __shfl_xor(mx, 16));
      mx = fmaxf(mx, __shfl_xor(mx, 32));
      if (lane < 16) redf[(jw * 4 + i) * 128 + dw * 64 + nt * 16 + lane] = mx;
    }
  }
  __syncthreads();
#pragma unroll
  for (int r = t; r < 512; r += 256) {
    int i = r >> 7, d = r & 127;
    float v = fmaxf(redf[i * 128 + d], redf[(4 + i) * 128 + d]);
    out[(f * Pn + i0 + i) * Dn + ct * 128 + d] = fmaxf(v + c2[ct * 128 + d], 0.f);
  }
}

// ---------------------------------------------------------------------------
extern "C" void kernel_launch(void* const* d_in, const int* in_sizes, int n_in,
                              void* d_out, int out_size, void* d_ws, size_t ws_size,
                              hipStream_t stream) {
  const float* hs    = (const float*)d_in[0];
  const float* pos   = (const float*)d_in[1];
  // d_in[2] seq_start_end: unused (equal-size frames, P=64)
  const float* We    = (const float*)d_in[3];
  const float* be    = (const float*)d_in[4];
  const float* W1    = (const float*)d_in[5];
  const float* b1    = (const float*)d_in[6];
  const float* g1    = (const float*)d_in[7];
  const float* beta1 = (const float*)d_in[8];
  const float* W2    = (const float*)d_in[9];
  const float* b2    = (const float*)d_in[10];
  const float* g2    = (const float*)d_in[11];
  const float* beta2 = (const float*)d_in[12];
  const float* rm1   = (const float*)d_in[13];
  const float* rv1   = (const float*)d_in[14];
  const float* rm2   = (const float*)d_in[15];
  const float* rv2   = (const float*)d_in[16];

  char* ws = (char*)d_ws;
  // layout: c2 4KB | Agb 2MB | Qgb 2MB | W2f 1MB
  float* c2 = (float*)(ws + 0);
  __hip_bfloat16* Agb = (__hip_bfloat16*)(ws + 4096);
  __hip_bfloat16* Qgb = (__hip_bfloat16*)(ws + 4096 + 2097152);
  uint4* W2f = (uint4*)(ws + 4096 + 2 * 2097152);
  float* out = (float*)d_out;

  prep_all<<<384, 512, 0, stream>>>(hs, pos, We, be, W1, b1, g1, beta1, rm1, rv1,
                                    W2, b2, g2, beta2, rm2, rv2, Agb, Qgb, W2f, c2);
  gemm_pool<<<dim3(Dn / 128, (Fn * Pn * Pn) / 256), 256, 0, stream>>>(Agb, Qgb, W2f, c2, out);
}

// Round 5
// 264.608 us; speedup vs baseline: 1.0648x; 1.0147x over previous
//
#include <hip/hip_runtime.h>
#include <hip/hip_bf16.h>
#include <stdint.h>

#define EPS_BN 1e-5f

constexpr int Fn = 32;    // frames
constexpr int Pn = 64;    // peds per frame
constexpr int Bn = 2048;  // batch
constexpr int Hn = 128;   // h_dim
constexpr int En = 64;    // embed dim
constexpr int Mn = 512;   // GEMM K
constexpr int Dn = 1024;  // GEMM N

using bf16x8  = __attribute__((ext_vector_type(8))) short;
using f32x16  = __attribute__((ext_vector_type(16))) float;

static __device__ __forceinline__ float    bcf(uint32_t u) { return __builtin_bit_cast(float, u); }
static __device__ __forceinline__ uint32_t bcu(float f)    { return __builtin_bit_cast(uint32_t, f); }
static __device__ __forceinline__ unsigned short bfbits(float f) {
  return __builtin_bit_cast(unsigned short, __float2bfloat16(f));
}

// async 16B/lane global -> LDS (wave-uniform LDS base; HW adds lane*16)
static __device__ __forceinline__ void dma16(const uint4* g, uint4* l) {
  __builtin_amdgcn_global_load_lds(
      (const __attribute__((address_space(1))) unsigned int*)g,
      (__attribute__((address_space(3))) unsigned int*)l, 16, 0, 0);
}

// af = bf16(relu(Ag - Qg)) from packed bf16 pairs (validated R2-R4)
static __device__ __forceinline__ bf16x8 mk_af(uint4 a, uint4 q) {
  uint4 x;
#pragma unroll
  for (int v = 0; v < 4; ++v) {
    uint32_t aw = ((const uint32_t*)&a)[v], qw = ((const uint32_t*)&q)[v];
    float lo = fmaxf(bcf(aw << 16) - bcf(qw << 16), 0.f);
    float hi = fmaxf(bcf(aw) - bcf(qw), 0.f);
    ((uint32_t*)&x)[v] = __builtin_amdgcn_perm(bcu(hi), bcu(lo), 0x07060302u);
  }
  return __builtin_bit_cast(bf16x8, x);
}

// ---------------------------------------------------------------------------
// prep_all: 640 blocks x 512 threads.
//  [0,512):  Agb/Qgb bf16 (4 batch rows/block), BN1+embedding folded.
//  [512,640): W2g in 32x32x16 MFMA B-fragment granule order + c2.
//   Granule (n32, ks): lane L holds 8 bf16 = W2[k][d]*s2[d],
//   d = n32*32 + (L&31), k = ks*16 + (L>>5)*8 + t (t=0..7).
// ---------------------------------------------------------------------------
__global__ void prep_all(const float* __restrict__ hs, const float* __restrict__ pos,
                         const float* __restrict__ We, const float* __restrict__ be,
                         const float* __restrict__ W1, const float* __restrict__ b1,
                         const float* __restrict__ g1, const float* __restrict__ beta1,
                         const float* __restrict__ rm1, const float* __restrict__ rv1,
                         const float* __restrict__ W2, const float* __restrict__ b2,
                         const float* __restrict__ g2, const float* __restrict__ beta2,
                         const float* __restrict__ rm2, const float* __restrict__ rv2,
                         __hip_bfloat16* __restrict__ Agb, __hip_bfloat16* __restrict__ Qgb,
                         uint4* __restrict__ W2g, float* __restrict__ c2) {
  __shared__ float smem[64 * 65];
  int bid = blockIdx.x, t = threadIdx.x;
  if (bid < 512) {
    int rb = bid * 4, m = t;  // 4 rows, m in [0,512)
    float* hsh = smem;        // 512 floats
    float* psh = smem + 512;  // 8 floats
    if (t < 4 * Hn) hsh[t] = hs[rb * Hn + t];
    if (t < 8) psh[t] = pos[rb * 2 + t];
    __syncthreads();
    float w0 = 0.f, w1 = 0.f, c = 0.f;
    for (int e = 0; e < En; ++e) {
      float w = W1[e * Mn + m];
      w0 += We[e] * w; w1 += We[En + e] * w; c += be[e] * w;
    }
    c += b1[m];
    float s  = g1[m] * rsqrtf(rv1[m] + EPS_BN);
    float tt = beta1[m] - rm1[m] * s;
    float acc[4];
#pragma unroll
    for (int ri = 0; ri < 4; ++ri) acc[ri] = c;
    for (int e = 0; e < Hn; ++e) {
      float w = W1[(En + e) * Mn + m];
#pragma unroll
      for (int ri = 0; ri < 4; ++ri) acc[ri] += hsh[ri * Hn + e] * w;
    }
#pragma unroll
    for (int ri = 0; ri < 4; ++ri) {
      float q = psh[ri * 2] * w0 + psh[ri * 2 + 1] * w1;
      Agb[(rb + ri) * Mn + m] = __float2bfloat16((acc[ri] + q) * s + tt);
      Qgb[(rb + ri) * Mn + m] = __float2bfloat16(q * s);
    }
  } else {
    // ---- W2 -> 32-col granules ----
    int b2i = bid - 512;                 // 0..127
    int d0 = (b2i & 15) * 64, k0 = (b2i >> 4) * 64;
    int col = t & 63, row8 = t >> 6;
#pragma unroll
    for (int rr = 0; rr < 8; ++rr) {
      int row = rr * 8 + row8;
      smem[row * 65 + col] = W2[(k0 + row) * Dn + d0 + col];  // [k_local][d_local]
    }
    __syncthreads();
    int lane = t & 63, q8 = t >> 6;      // 8 output slots per 64x64 tile
    int sel_n = q8 & 1, sel_ks = q8 >> 1;  // d-half, k-16-chunk
    int dl = sel_n * 32 + (lane & 31), d = d0 + dl;
    float sf = g2[d] * rsqrtf(rv2[d] + EPS_BN);
    int kb = sel_ks * 16 + (lane >> 5) * 8;
    uint32_t wd[4];
#pragma unroll
    for (int h = 0; h < 4; ++h) {
      uint32_t u0 = bfbits(smem[(kb + 2 * h) * 65 + dl] * sf);
      uint32_t u1 = bfbits(smem[(kb + 2 * h + 1) * 65 + dl] * sf);
      wd[h] = u0 | (u1 << 16);
    }
    int n32 = (d0 >> 5) + sel_n;         // 0..31
    int ks  = (k0 >> 4) + sel_ks;        // 0..31
    W2g[(n32 * 32 + ks) * 64 + lane] = (uint4){wd[0], wd[1], wd[2], wd[3]};
    if (k0 == 0 && t < 64) {
      int dd = d0 + t;
      float ss = g2[dd] * rsqrtf(rv2[dd] + EPS_BN);
      c2[dd] = b2[dd] * ss + beta2[dd] - rm2[dd] * ss;
    }
  }
}

// ---------------------------------------------------------------------------
// gemm_pool: 32x32x16 MFMA. Block = 4 i's x 64 j x 128 d; wave = ONE i,
// ALL 64 j (2 m-frags of 32 rows), 4 n-granules (128 d), acc 2x4x16 f32.
//  - af constructed in registers from global bf16 Agb/Qgb; zero construct
//    redundancy inside the block (each wave's af is unique to its i).
//  - B staged once per 256-k phase into 64KB LDS via global_load_lds;
//    barrier-free 8xK32 inner loop; A/Q reloaded into the same registers
//    right after each kstep's use (1-kc software pipeline, no reg doubling).
//  - Epilogue fully in-wave: max over 16 regs x 2 frags + shfl_xor(32),
//    +c2, relu, exclusive 32-lane write. No cross-wave reduction.
// ---------------------------------------------------------------------------
__launch_bounds__(256, 2)
__global__ void gemm_pool(const __hip_bfloat16* __restrict__ Agb,
                          const __hip_bfloat16* __restrict__ Qgb,
                          const uint4* __restrict__ W2g,
                          const float* __restrict__ c2, float* __restrict__ out) {
  __shared__ uint4 Bs[4096];  // 64KB: [ks_local(16)][nf(4)][lane(64)]

  int ct = blockIdx.x;   // 0..7   d-128 tile
  int rt = blockIdx.y;   // 0..511 (frame, i-quad)
  int f = rt >> 4, i0 = (rt & 15) * 4;

  int t = threadIdx.x, lane = t & 63, w = t >> 6;
  int i = i0 + w;                     // this wave's i
  int ko = lane >> 5;                 // k-octet selector (0/1)

  const uint4* aPj0 = (const uint4*)(Agb + (f * Pn + (lane & 31)) * Mn) + ko;       // j 0..31
  const uint4* aPj1 = (const uint4*)(Agb + (f * Pn + 32 + (lane & 31)) * Mn) + ko;  // j 32..63
  const uint4* qP   = (const uint4*)(Qgb + (f * Pn + i) * Mn) + ko;
  // B granule base for this block: n32 in [4ct, 4ct+4)
  const uint4* W2base = W2g + (size_t)(4 * ct) * 32 * 64 + lane;  // +(nf*32+ks)*64

  f32x16 acc[2][4];  // [jf][nf]
#pragma unroll
  for (int jf = 0; jf < 2; ++jf)
#pragma unroll
    for (int nf = 0; nf < 4; ++nf)
      acc[jf][nf] = (f32x16){0.f,0.f,0.f,0.f,0.f,0.f,0.f,0.f,0.f,0.f,0.f,0.f,0.f,0.f,0.f,0.f};

  // prologue: kc=0 A/Q (issued before DMAs; barrier drains all anyway)
  uint4 rA00 = aPj0[0], rA01 = aPj1[0], rQ0 = qP[0];   // kstep 0
  uint4 rA10 = aPj0[2], rA11 = aPj1[2], rQ1 = qP[2];   // kstep 1

  for (int ph = 0; ph < 2; ++ph) {
    if (ph) __syncthreads();  // all waves done reading Bs (phase 0)
    // stage this phase's 64KB of B: wave w stages slots [16w, 16w+16)
#pragma unroll
    for (int s = 0; s < 16; ++s) {
      int slot = w * 16 + s;
      int ksl = slot >> 2, nf = slot & 3;
      dma16(W2base + (nf * 32 + ph * 16 + ksl) * 64, Bs + slot * 64);
    }
    __syncthreads();  // vmcnt(0)+lgkmcnt(0) drain: Bs ready

    for (int kc8 = 0; kc8 < 8; ++kc8) {
      int kc = ph * 8 + kc8;
      int kn = (kc < 15) ? kc + 1 : 15;
      // ---- kstep 0 ----
      {
        bf16x8 af0 = mk_af(rA00, rQ0);
        bf16x8 af1 = mk_af(rA01, rQ0);
#pragma unroll
        for (int nf = 0; nf < 4; ++nf) {
          bf16x8 bg = *(const bf16x8*)(Bs + ((kc8 * 2 + 0) * 4 + nf) * 64 + lane);
          acc[0][nf] = __builtin_amdgcn_mfma_f32_32x32x16_bf16(af0, bg, acc[0][nf], 0, 0, 0);
          acc[1][nf] = __builtin_amdgcn_mfma_f32_32x32x16_bf16(af1, bg, acc[1][nf], 0, 0, 0);
        }
      }
      // reload kstep-0 regs for kc+1 (consumed next iteration)
      rA00 = aPj0[kn * 4]; rA01 = aPj1[kn * 4]; rQ0 = qP[kn * 4];
      // ---- kstep 1 ----
      {
        bf16x8 af0 = mk_af(rA10, rQ1);
        bf16x8 af1 = mk_af(rA11, rQ1);
#pragma unroll
        for (int nf = 0; nf < 4; ++nf) {
          bf16x8 bg = *(const bf16x8*)(Bs + ((kc8 * 2 + 1) * 4 + nf) * 64 + lane);
          acc[0][nf] = __builtin_amdgcn_mfma_f32_32x32x16_bf16(af0, bg, acc[0][nf], 0, 0, 0);
          acc[1][nf] = __builtin_amdgcn_mfma_f32_32x32x16_bf16(af1, bg, acc[1][nf], 0, 0, 0);
        }
      }
      rA10 = aPj0[kn * 4 + 2]; rA11 = aPj1[kn * 4 + 2]; rQ1 = qP[kn * 4 + 2];
    }
  }

  // ---- epilogue (fully in-wave): max over 64 j, +c2, relu, write ----
  // C layout (32x32): col = lane&31, row = (reg&3) + 8*(reg>>2) + 4*(lane>>5).
  // Union over reg (16) and lane>>5 (2, via shfl_xor 32) covers rows 0..31;
  // union over jf covers j 0..63.
#pragma unroll
  for (int nf = 0; nf < 4; ++nf) {
    float mx = 0.f;  // relu floor: max(0, .) == max_j relu(.)
#pragma unroll
    for (int jf = 0; jf < 2; ++jf)
#pragma unroll
      for (int rg = 0; rg < 16; ++rg)
        mx = fmaxf(mx, acc[jf][nf][rg]);
    mx = fmaxf(mx, __shfl_xor(mx, 32));
    if (lane < 32) {
      int d = ct * 128 + nf * 32 + (lane & 31);
      out[(f * Pn + i) * Dn + d] = fmaxf(mx + c2[d], 0.f);
    }
  }
}

// ---------------------------------------------------------------------------
extern "C" void kernel_launch(void* const* d_in, const int* in_sizes, int n_in,
                              void* d_out, int out_size, void* d_ws, size_t ws_size,
                              hipStream_t stream) {
  const float* hs    = (const float*)d_in[0];
  const float* pos   = (const float*)d_in[1];
  // d_in[2] seq_start_end: unused (equal-size frames, P=64)
  const float* We    = (const float*)d_in[3];
  const float* be    = (const float*)d_in[4];
  const float* W1    = (const float*)d_in[5];
  const float* b1    = (const float*)d_in[6];
  const float* g1    = (const float*)d_in[7];
  const float* beta1 = (const float*)d_in[8];
  const float* W2    = (const float*)d_in[9];
  const float* b2    = (const float*)d_in[10];
  const float* g2    = (const float*)d_in[11];
  const float* beta2 = (const float*)d_in[12];
  const float* rm1   = (const float*)d_in[13];
  const float* rv1   = (const float*)d_in[14];
  const float* rm2   = (const float*)d_in[15];
  const float* rv2   = (const float*)d_in[16];

  char* ws = (char*)d_ws;
  // layout: c2 4KB | Agb 2MB | Qgb 2MB | W2g 1MB
  float* c2 = (float*)(ws + 0);
  __hip_bfloat16* Agb = (__hip_bfloat16*)(ws + 4096);
  __hip_bfloat16* Qgb = (__hip_bfloat16*)(ws + 4096 + 2097152);
  uint4* W2g = (uint4*)(ws + 4096 + 2 * 2097152);
  float* out = (float*)d_out;

  prep_all<<<640, 512, 0, stream>>>(hs, pos, We, be, W1, b1, g1, beta1, rm1, rv1,
                                    W2, b2, g2, beta2, rm2, rv2, Agb, Qgb, W2g, c2);
  gemm_pool<<<dim3(Dn / 128, (Fn * Pn * Pn) / 256), 256, 0, stream>>>(Agb, Qgb, W2g, c2, out);
}

// Round 6
// 250.480 us; speedup vs baseline: 1.1249x; 1.0564x over previous
//
#include <hip/hip_runtime.h>
#include <hip/hip_bf16.h>
#include <stdint.h>

#define EPS_BN 1e-5f

constexpr int Fn = 32;    // frames
constexpr int Pn = 64;    // peds per frame
constexpr int Bn = 2048;  // batch
constexpr int Hn = 128;   // h_dim
constexpr int En = 64;    // embed dim
constexpr int Mn = 512;   // GEMM K
constexpr int Dn = 1024;  // GEMM N

using bf16x8  = __attribute__((ext_vector_type(8))) short;
using f32x16  = __attribute__((ext_vector_type(16))) float;

static __device__ __forceinline__ float    bcf(uint32_t u) { return __builtin_bit_cast(float, u); }
static __device__ __forceinline__ uint32_t bcu(float f)    { return __builtin_bit_cast(uint32_t, f); }
static __device__ __forceinline__ unsigned short bfbits(float f) {
  return __builtin_bit_cast(unsigned short, __float2bfloat16(f));
}

// async 16B/lane global -> LDS (wave-uniform LDS base; HW adds lane*16)
static __device__ __forceinline__ void dma16(const uint4* g, const uint4* l) {
  __builtin_amdgcn_global_load_lds(
      (const __attribute__((address_space(1))) unsigned int*)g,
      (__attribute__((address_space(3))) unsigned int*)l, 16, 0, 0);
}

// af = bf16(relu(Ag - Qg)) from packed bf16 pairs (validated R2-R5)
static __device__ __forceinline__ bf16x8 mk_af(uint4 a, uint4 q) {
  uint4 x;
#pragma unroll
  for (int v = 0; v < 4; ++v) {
    uint32_t aw = ((const uint32_t*)&a)[v], qw = ((const uint32_t*)&q)[v];
    float lo = fmaxf(bcf(aw << 16) - bcf(qw << 16), 0.f);
    float hi = fmaxf(bcf(aw) - bcf(qw), 0.f);
    ((uint32_t*)&x)[v] = __builtin_amdgcn_perm(bcu(hi), bcu(lo), 0x07060302u);
  }
  return __builtin_bit_cast(bf16x8, x);
}

// ---------------------------------------------------------------------------
// prep_all (unchanged from R5): 640 blocks x 512 threads.
//  [0,512):  Agb/Qgb bf16 (4 batch rows/block), BN1+embedding folded.
//  [512,640): W2g in 32x32x16 MFMA B-fragment granule order + c2.
//   Granule (n32, ks): lane L holds 8 bf16 = W2[k][d]*s2[d],
//   d = n32*32 + (L&31), k = ks*16 + (L>>5)*8 + t (t=0..7).
// ---------------------------------------------------------------------------
__global__ void prep_all(const float* __restrict__ hs, const float* __restrict__ pos,
                         const float* __restrict__ We, const float* __restrict__ be,
                         const float* __restrict__ W1, const float* __restrict__ b1,
                         const float* __restrict__ g1, const float* __restrict__ beta1,
                         const float* __restrict__ rm1, const float* __restrict__ rv1,
                         const float* __restrict__ W2, const float* __restrict__ b2,
                         const float* __restrict__ g2, const float* __restrict__ beta2,
                         const float* __restrict__ rm2, const float* __restrict__ rv2,
                         __hip_bfloat16* __restrict__ Agb, __hip_bfloat16* __restrict__ Qgb,
                         uint4* __restrict__ W2g, float* __restrict__ c2) {
  __shared__ float smem[64 * 65];
  int bid = blockIdx.x, t = threadIdx.x;
  if (bid < 512) {
    int rb = bid * 4, m = t;  // 4 rows, m in [0,512)
    float* hsh = smem;        // 512 floats
    float* psh = smem + 512;  // 8 floats
    if (t < 4 * Hn) hsh[t] = hs[rb * Hn + t];
    if (t < 8) psh[t] = pos[rb * 2 + t];
    __syncthreads();
    float w0 = 0.f, w1 = 0.f, c = 0.f;
    for (int e = 0; e < En; ++e) {
      float w = W1[e * Mn + m];
      w0 += We[e] * w; w1 += We[En + e] * w; c += be[e] * w;
    }
    c += b1[m];
    float s  = g1[m] * rsqrtf(rv1[m] + EPS_BN);
    float tt = beta1[m] - rm1[m] * s;
    float acc[4];
#pragma unroll
    for (int ri = 0; ri < 4; ++ri) acc[ri] = c;
    for (int e = 0; e < Hn; ++e) {
      float w = W1[(En + e) * Mn + m];
#pragma unroll
      for (int ri = 0; ri < 4; ++ri) acc[ri] += hsh[ri * Hn + e] * w;
    }
#pragma unroll
    for (int ri = 0; ri < 4; ++ri) {
      float q = psh[ri * 2] * w0 + psh[ri * 2 + 1] * w1;
      Agb[(rb + ri) * Mn + m] = __float2bfloat16((acc[ri] + q) * s + tt);
      Qgb[(rb + ri) * Mn + m] = __float2bfloat16(q * s);
    }
  } else {
    // ---- W2 -> 32-col granules ----
    int b2i = bid - 512;                 // 0..127
    int d0 = (b2i & 15) * 64, k0 = (b2i >> 4) * 64;
    int col = t & 63, row8 = t >> 6;
#pragma unroll
    for (int rr = 0; rr < 8; ++rr) {
      int row = rr * 8 + row8;
      smem[row * 65 + col] = W2[(k0 + row) * Dn + d0 + col];  // [k_local][d_local]
    }
    __syncthreads();
    int lane = t & 63, q8 = t >> 6;      // 8 output slots per 64x64 tile
    int sel_n = q8 & 1, sel_ks = q8 >> 1;  // d-half, k-16-chunk
    int dl = sel_n * 32 + (lane & 31), d = d0 + dl;
    float sf = g2[d] * rsqrtf(rv2[d] + EPS_BN);
    int kb = sel_ks * 16 + (lane >> 5) * 8;
    uint32_t wd[4];
#pragma unroll
    for (int h = 0; h < 4; ++h) {
      uint32_t u0 = bfbits(smem[(kb + 2 * h) * 65 + dl] * sf);
      uint32_t u1 = bfbits(smem[(kb + 2 * h + 1) * 65 + dl] * sf);
      wd[h] = u0 | (u1 << 16);
    }
    int n32 = (d0 >> 5) + sel_n;         // 0..31
    int ks  = (k0 >> 4) + sel_ks;        // 0..31
    W2g[(n32 * 32 + ks) * 64 + lane] = (uint4){wd[0], wd[1], wd[2], wd[3]};
    if (k0 == 0 && t < 64) {
      int dd = d0 + t;
      float ss = g2[dd] * rsqrtf(rv2[dd] + EPS_BN);
      c2[dd] = b2[dd] * ss + beta2[dd] - rm2[dd] * ss;
    }
  }
}

// ---------------------------------------------------------------------------
// gemm_pool: 32x32x16 MFMA. Block = 4 i x 64 j x 128 d; wave = one i, all j.
//  - A (frame-shared, i-independent) staged to LDS via global_load_lds in
//    A-fragment granule order: half-K (32KB) at prologue, re-staged at mid-K.
//  - B staged quarter-K (32KB) per phase. LDS = 64KB exactly. All slots are
//    1KB lane-contiguous granules -> conflict-free ds_read_b128, immediate
//    ds offsets (loops fully unrolled).
//  - Only per-kstep global load: ONE Q dwordx4, prefetched 1 kc (2 ksteps)
//    ahead. 7 drain barriers per block total; no other waits in the K-loop.
//  - Epilogue fully in-wave (max over j regs + shfl_xor 32), +c2, relu.
// ---------------------------------------------------------------------------
__launch_bounds__(256, 2)
__global__ void gemm_pool(const __hip_bfloat16* __restrict__ Agb,
                          const __hip_bfloat16* __restrict__ Qgb,
                          const uint4* __restrict__ W2g,
                          const float* __restrict__ c2, float* __restrict__ out) {
  __shared__ uint4 SH[4096];  // [0,2048): A slots, [2048,4096): B slots. 64KB.

  int ct = blockIdx.x;   // 0..7   d-128 tile
  int rt = blockIdx.y;   // 0..511 (frame, i-quad)
  int f = rt >> 4, i0 = (rt & 15) * 4;

  int t = threadIdx.x, lane = t & 63, w = t >> 6;
  int i = i0 + w;                     // this wave's i

  // A dma: slot sa=(kcA*2+kst)*2+jf (kcA=kc&7), lane L <- Agb row jf*32+(L&31),
  //        uint4 col kcA*4+kst*2+(L>>5). Per-lane constant part:
  const uint4* Au4 = (const uint4*)(Agb + (size_t)f * Pn * Mn);
  const uint4* aGL = Au4 + (size_t)(lane & 31) * 64 + (lane >> 5);
  // B dma: slot sb=(kq*4+nf), kq=kcl*2+kst, ks=sp*8+kq,
  //        g = W2g + ((4ct+nf)*32+ks)*64 + lane
  const uint4* bGL = W2g + (size_t)(4 * ct) * 32 * 64 + lane;
  // Q: per-kstep frag = qP[kc*4 + kst*2]
  const uint4* qP = (const uint4*)(Qgb + (size_t)(f * Pn + i) * Mn) + (lane >> 5);

  // ---- prologue: stage A(kc 0..8) [8 dma/wave] + B(phase 0) [8 dma/wave] ----
#pragma unroll
  for (int s = 0; s < 8; ++s) {
    int sa = w * 8 + s;                     // 0..31
    int kcA = sa >> 2, kst = (sa >> 1) & 1, jf = sa & 1;
    dma16(aGL + (size_t)jf * 32 * 64 + kcA * 4 + kst * 2, SH + sa * 64);
  }
#pragma unroll
  for (int s = 0; s < 8; ++s) {
    int sb = w * 8 + s;                     // 0..31
    int kq = sb >> 2, nf = sb & 3;          // ks = kq (phase 0)
    dma16(bGL + (nf * 32 + kq) * 64, SH + 2048 + sb * 64);
  }
  uint4 qc0 = qP[0], qc1 = qP[2];           // kc=0 Q frags

  f32x16 acc[2][4];  // [jf][nf]
#pragma unroll
  for (int jf = 0; jf < 2; ++jf)
#pragma unroll
    for (int nf = 0; nf < 4; ++nf)
      acc[jf][nf] = (f32x16){0.f,0.f,0.f,0.f,0.f,0.f,0.f,0.f,0.f,0.f,0.f,0.f,0.f,0.f,0.f,0.f};

  __syncthreads();  // drain: A(0..8), B(ph0), qc ready

#pragma unroll
  for (int sp = 0; sp < 4; ++sp) {
    if (sp) {
      __syncthreads();  // readers done with B(sp-1) (and A(0..8) when sp==2)
      if (sp == 2) {
#pragma unroll
        for (int s = 0; s < 8; ++s) {
          int sa = w * 8 + s;
          int kcA = sa >> 2, kst = (sa >> 1) & 1, jf = sa & 1;
          dma16(aGL + (size_t)jf * 32 * 64 + (kcA + 8) * 4 + kst * 2, SH + sa * 64);
        }
      }
#pragma unroll
      for (int s = 0; s < 8; ++s) {
        int sb = w * 8 + s;
        int kq = sb >> 2, nf = sb & 3;
        dma16(bGL + (nf * 32 + sp * 8 + kq) * 64, SH + 2048 + sb * 64);
      }
      __syncthreads();  // drain staged data
    }
#pragma unroll
    for (int kcl = 0; kcl < 4; ++kcl) {
      int kc = sp * 4 + kcl;
      // prefetch Q for kc+1 (consumed 2 ksteps later)
      int kn = (kc < 15) ? kc + 1 : 15;
      uint4 qn0 = qP[kn * 4], qn1 = qP[kn * 4 + 2];
#pragma unroll
      for (int kst = 0; kst < 2; ++kst) {
        int aBase = (((kc & 7) * 2 + kst) * 2) * 64 + lane;
        uint4 a0 = SH[aBase];
        uint4 a1 = SH[aBase + 64];
        int bBase = 2048 + ((kcl * 2 + kst) * 4) * 64 + lane;
        uint4 q = kst ? qc1 : qc0;
        bf16x8 af0 = mk_af(a0, q);
        bf16x8 af1 = mk_af(a1, q);
#pragma unroll
        for (int nf = 0; nf < 4; ++nf) {
          bf16x8 bg = *(const bf16x8*)(SH + bBase + nf * 64);
          acc[0][nf] = __builtin_amdgcn_mfma_f32_32x32x16_bf16(af0, bg, acc[0][nf], 0, 0, 0);
          acc[1][nf] = __builtin_amdgcn_mfma_f32_32x32x16_bf16(af1, bg, acc[1][nf], 0, 0, 0);
        }
      }
      qc0 = qn0; qc1 = qn1;
    }
  }

  // ---- epilogue (fully in-wave): max over 64 j, +c2, relu, write ----
  // C layout (32x32): col=lane&31, row=(reg&3)+8*(reg>>2)+4*(lane>>5);
  // union over reg(16) + shfl_xor(32) covers rows 0..31; jf covers j 32..63.
#pragma unroll
  for (int nf = 0; nf < 4; ++nf) {
    float mx = 0.f;  // relu floor: max(0,.) == max_j relu(.)
#pragma unroll
    for (int jf = 0; jf < 2; ++jf)
#pragma unroll
      for (int rg = 0; rg < 16; ++rg)
        mx = fmaxf(mx, acc[jf][nf][rg]);
    mx = fmaxf(mx, __shfl_xor(mx, 32));
    if (lane < 32) {
      int d = ct * 128 + nf * 32 + (lane & 31);
      out[(f * Pn + i) * Dn + d] = fmaxf(mx + c2[d], 0.f);
    }
  }
}

// ---------------------------------------------------------------------------
extern "C" void kernel_launch(void* const* d_in, const int* in_sizes, int n_in,
                              void* d_out, int out_size, void* d_ws, size_t ws_size,
                              hipStream_t stream) {
  const float* hs    = (const float*)d_in[0];
  const float* pos   = (const float*)d_in[1];
  // d_in[2] seq_start_end: unused (equal-size frames, P=64)
  const float* We    = (const float*)d_in[3];
  const float* be    = (const float*)d_in[4];
  const float* W1    = (const float*)d_in[5];
  const float* b1    = (const float*)d_in[6];
  const float* g1    = (const float*)d_in[7];
  const float* beta1 = (const float*)d_in[8];
  const float* W2    = (const float*)d_in[9];
  const float* b2    = (const float*)d_in[10];
  const float* g2    = (const float*)d_in[11];
  const float* beta2 = (const float*)d_in[12];
  const float* rm1   = (const float*)d_in[13];
  const float* rv1   = (const float*)d_in[14];
  const float* rm2   = (const float*)d_in[15];
  const float* rv2   = (const float*)d_in[16];

  char* ws = (char*)d_ws;
  // layout: c2 4KB | Agb 2MB | Qgb 2MB | W2g 1MB
  float* c2 = (float*)(ws + 0);
  __hip_bfloat16* Agb = (__hip_bfloat16*)(ws + 4096);
  __hip_bfloat16* Qgb = (__hip_bfloat16*)(ws + 4096 + 2097152);
  uint4* W2g = (uint4*)(ws + 4096 + 2 * 2097152);
  float* out = (float*)d_out;

  prep_all<<<640, 512, 0, stream>>>(hs, pos, We, be, W1, b1, g1, beta1, rm1, rv1,
                                    W2, b2, g2, beta2, rm2, rv2, Agb, Qgb, W2g, c2);
  gemm_pool<<<dim3(Dn / 128, (Fn * Pn * Pn) / 256), 256, 0, stream>>>(Agb, Qgb, W2g, c2, out);
}